// Round 14
// baseline (109.886 us; speedup 1.0000x reference)
//
#include <hip/hip_runtime.h>
#include <hip/hip_cooperative_groups.h>
#include <cstdint>

namespace cg = cooperative_groups;

#define NQ 8
#define NKV 16
#define NGRP 4            // kv rows split across 4 block groups
#define KPG (NKV / NGRP)  // 4 kv rows per group
#define NPB 40            // per-block partials: 8x4 products + 8 norms (g0)
#define NSUM 136          // final: 128 qk + 8 norms
#define NXCD 8

typedef float floatx4 __attribute__((ext_vector_type(4)));

// ---------------- Threefry-2x32 (JAX partitionable path; verified R3) ----
__device__ __forceinline__ unsigned rotl32(unsigned x, int d) {
    return (x << d) | (x >> (32 - d));
}

__device__ __forceinline__ void threefry2x32(unsigned k0, unsigned k1,
                                             unsigned& x0, unsigned& x1) {
    const unsigned ks0 = k0, ks1 = k1, ks2 = k0 ^ k1 ^ 0x1BD11BDAu;
    x0 += ks0; x1 += ks1;
    x0 += x1; x1 = rotl32(x1, 13); x1 ^= x0;
    x0 += x1; x1 = rotl32(x1, 15); x1 ^= x0;
    x0 += x1; x1 = rotl32(x1, 26); x1 ^= x0;
    x0 += x1; x1 = rotl32(x1,  6); x1 ^= x0;
    x0 += ks1; x1 += ks2 + 1u;
    x0 += x1; x1 = rotl32(x1, 17); x1 ^= x0;
    x0 += x1; x1 = rotl32(x1, 29); x1 ^= x0;
    x0 += x1; x1 = rotl32(x1, 16); x1 ^= x0;
    x0 += x1; x1 = rotl32(x1, 24); x1 ^= x0;
    x0 += ks2; x1 += ks0 + 2u;
    x0 += x1; x1 = rotl32(x1, 13); x1 ^= x0;
    x0 += x1; x1 = rotl32(x1, 15); x1 ^= x0;
    x0 += x1; x1 = rotl32(x1, 26); x1 ^= x0;
    x0 += x1; x1 = rotl32(x1,  6); x1 ^= x0;
    x0 += ks0; x1 += ks1 + 3u;
    x0 += x1; x1 = rotl32(x1, 17); x1 ^= x0;
    x0 += x1; x1 = rotl32(x1, 29); x1 ^= x0;
    x0 += x1; x1 = rotl32(x1, 16); x1 ^= x0;
    x0 += x1; x1 = rotl32(x1, 24); x1 ^= x0;
    x0 += ks1; x1 += ks2 + 4u;
    x0 += x1; x1 = rotl32(x1, 13); x1 ^= x0;
    x0 += x1; x1 = rotl32(x1, 15); x1 ^= x0;
    x0 += x1; x1 = rotl32(x1, 26); x1 ^= x0;
    x0 += x1; x1 = rotl32(x1,  6); x1 ^= x0;
    x0 += ks2; x1 += ks0 + 5u;
}

__device__ __forceinline__ int jax_keep_bit(int idx) {
    unsigned x0 = 0u, x1 = (unsigned)idx;
    threefry2x32(0u, 42u, x0, x1);
    unsigned bits = x0 ^ x1;
    unsigned fb = (bits >> 9) | 0x3F800000u;
    float u = __uint_as_float(fb) - 1.0f;
    return u < 0.9f ? 1 : 0;
}

__device__ __forceinline__ float dot4(float4 a, float4 b) {
    return a.x * b.x + a.y * b.y + a.z * b.z + a.w * b.w;
}

__device__ __forceinline__ float dot4v(float4 a, floatx4 b) {
    return a.x * b.x + a.y * b.y + a.z * b.z + a.w * b.w;
}

// ---------------- Phase 1: partial dots (R12-proven, untouched) ----------
// 4-way kv split, XCD-co-located groups, grid-stride, nontemporal kv loads.
__global__ __launch_bounds__(256, 4) void qk_partial_kernel(
    const float4* __restrict__ qkv, float* __restrict__ partial,
    unsigned D4, unsigned ncb)
{
    const int tid = threadIdx.x;
    const int w   = tid >> 6;
    const int lane = tid & 63;

    unsigned g, cb;
    if ((ncb & (NXCD - 1)) == 0) {
        const unsigned xcd = blockIdx.x & (NXCD - 1);
        const unsigned idx = blockIdx.x >> 3;
        g  = idx & (NGRP - 1);
        cb = (idx >> 2) * NXCD + xcd;
    } else {
        g  = blockIdx.x & (NGRP - 1);
        cb = blockIdx.x >> 2;
    }

    const floatx4* __restrict__ kbase =
        (const floatx4*)(qkv + (size_t)(NQ + g * KPG) * D4);

    float acc[NQ][KPG];
#pragma unroll
    for (int r = 0; r < NQ; ++r)
#pragma unroll
        for (int j = 0; j < KPG; ++j) acc[r][j] = 0.f;
    float nacc[NQ];
#pragma unroll
    for (int r = 0; r < NQ; ++r) nacc[r] = 0.f;

    const unsigned stride = ncb * 256u;

    for (unsigned v = cb * 256u + tid; v < D4; v += stride) {
        floatx4 kv[KPG];
#pragma unroll
        for (int j = 0; j < KPG; ++j)
            kv[j] = __builtin_nontemporal_load(&kbase[(size_t)j * D4 + v]);
        float4 qv[NQ];
#pragma unroll
        for (int r = 0; r < NQ; ++r)
            qv[r] = qkv[(size_t)r * D4 + v];

        if (g == 0) {
#pragma unroll
            for (int r = 0; r < NQ; ++r)
                nacc[r] += dot4(qv[r], qv[r]);
        }
#pragma unroll
        for (int r = 0; r < NQ; ++r)
#pragma unroll
            for (int j = 0; j < KPG; ++j)
                acc[r][j] += dot4v(qv[r], kv[j]);
    }

    // wave shuffle-reduce the 40 partials, cross-wave combine via LDS
    __shared__ float lred[4][NPB];
#pragma unroll
    for (int r = 0; r < NQ; ++r) {
#pragma unroll
        for (int j = 0; j < KPG; ++j) {
            float s = acc[r][j];
#pragma unroll
            for (int off = 32; off >= 1; off >>= 1)
                s += __shfl_xor(s, off, 64);
            if (lane == 0) lred[w][r * KPG + j] = s;
        }
    }
    if (g == 0) {
#pragma unroll
        for (int r = 0; r < NQ; ++r) {
            float s = nacc[r];
#pragma unroll
            for (int off = 32; off >= 1; off >>= 1)
                s += __shfl_xor(s, off, 64);
            if (lane == 0) lred[w][32 + r] = s;
        }
    } else if (lane == 0) {
#pragma unroll
        for (int r = 0; r < NQ; ++r) lred[w][32 + r] = 0.f;
    }
    __syncthreads();
    if (tid < NPB) {
        const float s = lred[0][tid] + lred[1][tid] + lred[2][tid] + lred[3][tid];
        partial[(size_t)(cb * NGRP + g) * NPB + tid] = s;
    }
}

// ---------------- Phase 2+3: cooperative reduce + finalize ----------------
// 136 blocks: block s reduces slot s over colblocks (R6-proven access
// pattern), grid.sync() (includes release/acquire), then block 0 runs the
// softmax+threefry tail. No atomics, no memset -> deterministic and no
// fillBuffer cost (R13 lesson: tiny hipMemsetAsync ~ huge fill dispatch).
__global__ __launch_bounds__(256) void reduce_finalize_kernel(
    const float* __restrict__ partial, float* __restrict__ sums,
    float* __restrict__ out, int ncb)
{
    const int s = blockIdx.x;  // 0..135
    const int tid = threadIdx.x;
    int g, slot;
    if (s < 128) {
        const int r = s >> 4, j = s & 15;
        g = j >> 2; slot = r * KPG + (j & 3);
    } else {
        g = 0; slot = 32 + (s - 128);
    }

    float acc = 0.f;
    for (int cb = tid; cb < ncb; cb += 256)
        acc += partial[(size_t)(cb * NGRP + g) * NPB + slot];

    float vsum = acc;
    for (int off = 32; off >= 1; off >>= 1)
        vsum += __shfl_xor(vsum, off, 64);

    __shared__ float red[4];
    const int w = tid >> 6, lane = tid & 63;
    if (lane == 0) red[w] = vsum;
    __syncthreads();
    if (tid == 0) sums[s] = red[0] + red[1] + red[2] + red[3];

    cg::this_grid().sync();

    if (blockIdx.x == 0 && tid < 128) {
        const int r = tid >> 4;
        const float norm = sums[128 + r];
        const float inv_scale = rsqrtf(norm + 1e-12f);
        const float logit = sums[tid] * inv_scale;

        float m = logit;
        for (int off = 8; off >= 1; off >>= 1)
            m = fmaxf(m, __shfl_xor(m, off, 64));
        const float e = expf(logit - m);
        float ssum = e;
        for (int off = 8; off >= 1; off >>= 1)
            ssum += __shfl_xor(ssum, off, 64);

        out[tid] = jax_keep_bit(tid) ? (e / ssum / 0.9f) : 0.f;
    }
}

// ---------------- Launch --------------------------------------------------
extern "C" void kernel_launch(void* const* d_in, const int* in_sizes, int n_in,
                              void* d_out, int out_size, void* d_ws, size_t ws_size,
                              hipStream_t stream) {
    const float* qkv = (const float*)d_in[0];
    float* out = (float*)d_out;

    const long long total = (long long)in_sizes[0];
    const unsigned D  = (unsigned)(total / (NQ + NKV));
    const unsigned D4 = D / 4;

    float* wsf = (float*)d_ws;
    const long long cap_floats = (long long)(ws_size / 4);

    unsigned ncb = 256;  // 256 colblocks x 4 groups = 1024 blocks, 1 round
    long long need = (long long)ncb * NGRP * NPB + NSUM;
    while (need > cap_floats && ncb > 1) {
        ncb >>= 1;
        need = (long long)ncb * NGRP * NPB + NSUM;
    }

    float* partial = wsf;
    float* sums    = wsf + (long long)ncb * NGRP * NPB;

    qk_partial_kernel<<<ncb * NGRP, 256, 0, stream>>>(
        (const float4*)qkv, partial, D4, ncb);

    int ncb_i = (int)ncb;
    void* args[] = { (void*)&partial, (void*)&sums, (void*)&out,
                     (void*)&ncb_i };
    hipLaunchCooperativeKernel((void*)reduce_finalize_kernel,
                               dim3(NSUM), dim3(256), args, 0, stream);
}

// Round 15
// 81.073 us; speedup vs baseline: 1.3554x; 1.3554x over previous
//
#include <hip/hip_runtime.h>
#include <cstdint>

#define NQ 8
#define NKV 16
#define NGRP 4            // kv rows split across 4 block groups
#define KPG (NKV / NGRP)  // 4 kv rows per group
#define NPB 40            // per-block partials: 8x4 products + 8 norms (g0)
#define NSUM 136          // final: 128 qk + 8 norms
#define NXCD 8

typedef float floatx4 __attribute__((ext_vector_type(4)));

// ---------------- Threefry-2x32 (JAX partitionable path; verified R3) ----
__device__ __forceinline__ unsigned rotl32(unsigned x, int d) {
    return (x << d) | (x >> (32 - d));
}

__device__ __forceinline__ void threefry2x32(unsigned k0, unsigned k1,
                                             unsigned& x0, unsigned& x1) {
    const unsigned ks0 = k0, ks1 = k1, ks2 = k0 ^ k1 ^ 0x1BD11BDAu;
    x0 += ks0; x1 += ks1;
    x0 += x1; x1 = rotl32(x1, 13); x1 ^= x0;
    x0 += x1; x1 = rotl32(x1, 15); x1 ^= x0;
    x0 += x1; x1 = rotl32(x1, 26); x1 ^= x0;
    x0 += x1; x1 = rotl32(x1,  6); x1 ^= x0;
    x0 += ks1; x1 += ks2 + 1u;
    x0 += x1; x1 = rotl32(x1, 17); x1 ^= x0;
    x0 += x1; x1 = rotl32(x1, 29); x1 ^= x0;
    x0 += x1; x1 = rotl32(x1, 16); x1 ^= x0;
    x0 += x1; x1 = rotl32(x1, 24); x1 ^= x0;
    x0 += ks2; x1 += ks0 + 2u;
    x0 += x1; x1 = rotl32(x1, 13); x1 ^= x0;
    x0 += x1; x1 = rotl32(x1, 15); x1 ^= x0;
    x0 += x1; x1 = rotl32(x1, 26); x1 ^= x0;
    x0 += x1; x1 = rotl32(x1,  6); x1 ^= x0;
    x0 += ks0; x1 += ks1 + 3u;
    x0 += x1; x1 = rotl32(x1, 17); x1 ^= x0;
    x0 += x1; x1 = rotl32(x1, 29); x1 ^= x0;
    x0 += x1; x1 = rotl32(x1, 16); x1 ^= x0;
    x0 += x1; x1 = rotl32(x1, 24); x1 ^= x0;
    x0 += ks1; x1 += ks2 + 4u;
    x0 += x1; x1 = rotl32(x1, 13); x1 ^= x0;
    x0 += x1; x1 = rotl32(x1, 15); x1 ^= x0;
    x0 += x1; x1 = rotl32(x1, 26); x1 ^= x0;
    x0 += x1; x1 = rotl32(x1,  6); x1 ^= x0;
    x0 += ks2; x1 += ks0 + 5u;
}

__device__ __forceinline__ int jax_keep_bit(int idx) {
    unsigned x0 = 0u, x1 = (unsigned)idx;
    threefry2x32(0u, 42u, x0, x1);
    unsigned bits = x0 ^ x1;
    unsigned fb = (bits >> 9) | 0x3F800000u;
    float u = __uint_as_float(fb) - 1.0f;
    return u < 0.9f ? 1 : 0;
}

__device__ __forceinline__ float dot4(float4 a, float4 b) {
    return a.x * b.x + a.y * b.y + a.z * b.z + a.w * b.w;
}

__device__ __forceinline__ float dot4v(float4 a, floatx4 b) {
    return a.x * b.x + a.y * b.y + a.z * b.z + a.w * b.w;
}

// ---------------- Phase 1: partial dots (R12-proven) ---------------------
// 4-way kv split, XCD-co-located groups (the 4 g-blocks of one colblock have
// bids differing by 8 -> same XCD under round-robin -> q re-reads hit L2),
// grid-stride, nontemporal kv loads (zero-reuse stream stops evicting q/L3).
__global__ __launch_bounds__(256, 4) void qk_partial_kernel(
    const float4* __restrict__ qkv, float* __restrict__ partial,
    unsigned D4, unsigned ncb)
{
    const int tid = threadIdx.x;
    const int w   = tid >> 6;
    const int lane = tid & 63;

    unsigned g, cb;
    if ((ncb & (NXCD - 1)) == 0) {
        const unsigned xcd = blockIdx.x & (NXCD - 1);
        const unsigned idx = blockIdx.x >> 3;
        g  = idx & (NGRP - 1);
        cb = (idx >> 2) * NXCD + xcd;
    } else {
        g  = blockIdx.x & (NGRP - 1);
        cb = blockIdx.x >> 2;
    }

    const floatx4* __restrict__ kbase =
        (const floatx4*)(qkv + (size_t)(NQ + g * KPG) * D4);

    float acc[NQ][KPG];
#pragma unroll
    for (int r = 0; r < NQ; ++r)
#pragma unroll
        for (int j = 0; j < KPG; ++j) acc[r][j] = 0.f;
    float nacc[NQ];
#pragma unroll
    for (int r = 0; r < NQ; ++r) nacc[r] = 0.f;

    const unsigned stride = ncb * 256u;

    for (unsigned v = cb * 256u + tid; v < D4; v += stride) {
        floatx4 kv[KPG];
#pragma unroll
        for (int j = 0; j < KPG; ++j)
            kv[j] = __builtin_nontemporal_load(&kbase[(size_t)j * D4 + v]);
        float4 qv[NQ];
#pragma unroll
        for (int r = 0; r < NQ; ++r)
            qv[r] = qkv[(size_t)r * D4 + v];

        if (g == 0) {
#pragma unroll
            for (int r = 0; r < NQ; ++r)
                nacc[r] += dot4(qv[r], qv[r]);
        }
#pragma unroll
        for (int r = 0; r < NQ; ++r)
#pragma unroll
            for (int j = 0; j < KPG; ++j)
                acc[r][j] += dot4v(qv[r], kv[j]);
    }

    // wave shuffle-reduce the 40 partials, cross-wave combine via LDS
    __shared__ float lred[4][NPB];
#pragma unroll
    for (int r = 0; r < NQ; ++r) {
#pragma unroll
        for (int j = 0; j < KPG; ++j) {
            float s = acc[r][j];
#pragma unroll
            for (int off = 32; off >= 1; off >>= 1)
                s += __shfl_xor(s, off, 64);
            if (lane == 0) lred[w][r * KPG + j] = s;
        }
    }
    if (g == 0) {
#pragma unroll
        for (int r = 0; r < NQ; ++r) {
            float s = nacc[r];
#pragma unroll
            for (int off = 32; off >= 1; off >>= 1)
                s += __shfl_xor(s, off, 64);
            if (lane == 0) lred[w][32 + r] = s;
        }
    } else if (lane == 0) {
#pragma unroll
        for (int r = 0; r < NQ; ++r) lred[w][32 + r] = 0.f;
    }
    __syncthreads();
    if (tid < NPB) {
        const float s = lred[0][tid] + lred[1][tid] + lred[2][tid] + lred[3][tid];
        partial[(size_t)(cb * NGRP + g) * NPB + tid] = s;
    }
}

// ---------------- Phase 2: reduce partials across colblocks ---------------
__global__ __launch_bounds__(256) void reduce_kernel(
    const float* __restrict__ partial, float* __restrict__ sums, int ncb)
{
    const int s = blockIdx.x;  // 0..135
    int g, slot;
    if (s < 128) {
        const int r = s >> 4, j = s & 15;
        g = j >> 2; slot = r * KPG + (j & 3);
    } else {
        g = 0; slot = 32 + (s - 128);
    }

    float acc = 0.f;
    for (int cb = threadIdx.x; cb < ncb; cb += 256)
        acc += partial[(size_t)(cb * NGRP + g) * NPB + slot];

    float vsum = acc;
    for (int off = 32; off >= 1; off >>= 1)
        vsum += __shfl_xor(vsum, off, 64);

    __shared__ float red[4];
    const int w = threadIdx.x >> 6, lane = threadIdx.x & 63;
    if (lane == 0) red[w] = vsum;
    __syncthreads();
    if (threadIdx.x == 0) sums[s] = red[0] + red[1] + red[2] + red[3];
}

// ---------------- Phase 3: scale, softmax, dropout ------------------------
__global__ __launch_bounds__(128) void finalize_kernel(
    const float* __restrict__ sums, float* __restrict__ out)
{
    const int idx = threadIdx.x;  // 0..127
    const int r = idx >> 4;

    const float norm = sums[128 + r];
    const float inv_scale = rsqrtf(norm + 1e-12f);
    const float logit = sums[idx] * inv_scale;

    float m = logit;
    for (int off = 8; off >= 1; off >>= 1)
        m = fmaxf(m, __shfl_xor(m, off, 64));
    const float e = expf(logit - m);
    float ssum = e;
    for (int off = 8; off >= 1; off >>= 1)
        ssum += __shfl_xor(ssum, off, 64);
    const float sm = e / ssum;

    out[idx] = jax_keep_bit(idx) ? (sm / 0.9f) : 0.f;
}

// ---------------- Launch --------------------------------------------------
extern "C" void kernel_launch(void* const* d_in, const int* in_sizes, int n_in,
                              void* d_out, int out_size, void* d_ws, size_t ws_size,
                              hipStream_t stream) {
    const float* qkv = (const float*)d_in[0];
    float* out = (float*)d_out;

    const long long total = (long long)in_sizes[0];
    const unsigned D  = (unsigned)(total / (NQ + NKV));
    const unsigned D4 = D / 4;

    float* wsf = (float*)d_ws;
    const long long cap_floats = (long long)(ws_size / 4);

    unsigned ncb = 256;  // 256 colblocks x 4 groups = 1024 blocks, 1 round
    long long need = (long long)ncb * NGRP * NPB + NSUM;
    while (need > cap_floats && ncb > 1) {
        ncb >>= 1;
        need = (long long)ncb * NGRP * NPB + NSUM;
    }

    float* partial = wsf;
    float* sums    = wsf + (long long)ncb * NGRP * NPB;

    qk_partial_kernel<<<ncb * NGRP, 256, 0, stream>>>(
        (const float4*)qkv, partial, D4, ncb);
    reduce_kernel<<<NSUM, 256, 0, stream>>>(partial, sums, (int)ncb);
    finalize_kernel<<<1, 128, 0, stream>>>(sums, out);
}